// Round 13
// baseline (499.530 us; speedup 1.0000x reference)
//
#include <hip/hip_runtime.h>
#include <hip/hip_bf16.h>
#include <cstdint>
#include <cstddef>

#define B_ 4
#define N_ 10000
#define E_ 160000
#define H_ 128
#define HEADS_ 4
#define HH_ 512
#define NROWS (B_*N_)

typedef __attribute__((ext_vector_type(8))) short bf16x8;
typedef __attribute__((ext_vector_type(4))) float f32x4;
typedef __attribute__((ext_vector_type(2))) float f32x2;

__device__ __forceinline__ float lrelu(float x){ return x > 0.f ? x : 0.2f*x; }
__device__ __forceinline__ unsigned short f2b(float f){
  unsigned int u = __builtin_bit_cast(unsigned int, f);
  unsigned int r = (u + 0x7fffu + ((u >> 16) & 1u)) >> 16;
  return (unsigned short)r;
}
__device__ __forceinline__ float blo(unsigned int u){ return __builtin_bit_cast(float, u << 16); }
__device__ __forceinline__ float bhi(unsigned int u){ return __builtin_bit_cast(float, u & 0xffff0000u); }

__device__ __forceinline__ void acc_row(f32x2* ac, float al, uint4 h){
  f32x2 v = {al, al};
  ac[0] += v * (f32x2){blo(h.x), bhi(h.x)};
  ac[1] += v * (f32x2){blo(h.y), bhi(h.y)};
  ac[2] += v * (f32x2){blo(h.z), bhi(h.z)};
  ac[3] += v * (f32x2){blo(h.w), bhi(h.w)};
}

// ---------------- CSR build ----------------
__global__ void k_count(const int* __restrict__ tgt, int* __restrict__ cnt){
  int e = blockIdx.x*blockDim.x + threadIdx.x;
  int b = blockIdx.y;
  int t = tgt[(size_t)b*E_ + e];
  atomicAdd(&cnt[b*N_ + t], 1);
}

__global__ void k_scan(const int* __restrict__ cnt, int* __restrict__ off, int* __restrict__ cursor){
  int b = blockIdx.x;
  __shared__ int wsum[16];
  __shared__ int carry_s;
  int lane = threadIdx.x & 63, wid = threadIdx.x >> 6;
  if (threadIdx.x == 0){ carry_s = 0; off[b*(N_+1)] = 0; }
  __syncthreads();
  for (int base = 0; base < N_; base += 1024){
    int i = base + threadIdx.x;
    int v = (i < N_) ? cnt[b*N_ + i] : 0;
    int x = v;
    #pragma unroll
    for (int d = 1; d < 64; d <<= 1){
      int y = __shfl_up(x, d);
      if (lane >= d) x += y;
    }
    if (lane == 63) wsum[wid] = x;
    __syncthreads();
    if (wid == 0 && lane < 16){
      int w = wsum[lane];
      #pragma unroll
      for (int d = 1; d < 16; d <<= 1){
        int y = __shfl_up(w, d, 16);
        if (lane >= d) w += y;
      }
      wsum[lane] = w;
    }
    __syncthreads();
    int excl = (wid ? wsum[wid-1] : 0) + carry_s;
    if (i < N_){
      int inc = x + excl;
      off[b*(N_+1) + i + 1] = inc;
      cursor[b*N_ + i] = inc - v;
    }
    __syncthreads();
    if (threadIdx.x == 0) carry_s += wsum[15];
    __syncthreads();
  }
}

__global__ void k_scatter(const int* __restrict__ src, const int* __restrict__ tgt,
                          int* __restrict__ cursor, int* __restrict__ csr){
  int e = blockIdx.x*blockDim.x + threadIdx.x;
  int b = blockIdx.y;
  int t = tgt[(size_t)b*E_ + e];
  int pos = atomicAdd(&cursor[b*N_ + t], 1);
  csr[(size_t)b*E_ + pos] = src[(size_t)b*E_ + e];
}

// ---------------- prep: Wa tables + W transpose/cast, all 3 layers ----------------
__global__ void k_prep(const float* __restrict__ W0, const float* __restrict__ W1, const float* __restrict__ W2,
                       const float* __restrict__ as0, const float* __restrict__ as1, const float* __restrict__ as2,
                       const float* __restrict__ ad0, const float* __restrict__ ad1, const float* __restrict__ ad2,
                       float* __restrict__ wasA, float* __restrict__ wadA, unsigned short* __restrict__ wtA){
  int l = blockIdx.y;
  const float* W   = (l==0)?W0:(l==1)?W1:W2;
  const float* asp = (l==0)?as0:(l==1)?as1:as2;
  const float* adp = (l==0)?ad0:(l==1)?ad1:ad2;
  if (blockIdx.x < 256){
    int i = blockIdx.x*256 + threadIdx.x;     // i = c*H_ + k
    int c = i >> 7, k = i & 127;
    wtA[(size_t)l*HH_*H_ + i] = f2b(W[(size_t)k*HH_ + c]);
  } else {
    int j = (blockIdx.x - 256)*256 + threadIdx.x;   // j = k*4 + h
    if (j < H_*HEADS_){
      int k = j >> 2, h = j & 3;
      const float* wrow = W + (size_t)k*HH_ + h*H_;
      const float* asr = asp + h*H_;
      const float* adr = adp + h*H_;
      float ss = 0.f, sd = 0.f;
      for (int c = 0; c < H_; ++c){ float w = wrow[c]; ss += w*asr[c]; sd += w*adr[c]; }
      wasA[l*HH_ + j] = ss; wadA[l*HH_ + j] = sd;
    }
  }
}

// ---------------- layer-1: cast x->bf16 + logits (one wave per row) ----------------
__global__ __launch_bounds__(256) void k_cast_logits(const float* __restrict__ X,
    const float* __restrict__ was, const float* __restrict__ wad,
    unsigned short* __restrict__ Xb, float* __restrict__ es, float* __restrict__ ed){
  int gw = (blockIdx.x*blockDim.x + threadIdx.x) >> 6;
  int lane = threadIdx.x & 63;
  float2 v = *(const float2*)(X + (size_t)gw*H_ + lane*2);
  unsigned int o = ((unsigned int)f2b(v.y) << 16) | (unsigned int)f2b(v.x);
  *(unsigned int*)(Xb + (size_t)gw*H_ + lane*2) = o;
  int c = lane*2;
  const f32x4* w4 = (const f32x4*)was;
  const f32x4* d4 = (const f32x4*)wad;
  f32x4 se = v.x*w4[c] + v.y*w4[c+1];
  f32x4 de = v.x*d4[c] + v.y*d4[c+1];
  #pragma unroll
  for (int d = 1; d < 64; d <<= 1){
    se.x += __shfl_xor(se.x,d); se.y += __shfl_xor(se.y,d);
    se.z += __shfl_xor(se.z,d); se.w += __shfl_xor(se.w,d);
    de.x += __shfl_xor(de.x,d); de.y += __shfl_xor(de.y,d);
    de.z += __shfl_xor(de.z,d); de.w += __shfl_xor(de.w,d);
  }
  if (lane == 0){
    *(float4*)(es + (size_t)gw*4) = make_float4(se.x, se.y, se.z, se.w);
    *(float4*)(ed + (size_t)gw*4) = make_float4(de.x, de.y, de.z, de.w);
  }
}

// ---- h = x @ W: one block = 64 rows x all 512 cols; X staged once, Wt dbuf-looped. ----
__global__ __launch_bounds__(256) void k_gemm_mfma(const unsigned short* __restrict__ Xb,
    const unsigned short* __restrict__ Wt, unsigned short* __restrict__ Hb){
  __shared__ unsigned short xs[64*128];        // 16 KB
  __shared__ unsigned short ws[2][64*128];     // 32 KB double buffer
  int idx = blockIdx.x;
  int g = (idx & 7) >> 1;
  int j = ((idx >> 3) << 1) | (idx & 1);
  if (j >= 157) return;
  int rmax = N_ - j*64; if (rmax > 64) rmax = 64;
  size_t row0 = (size_t)g*N_ + (size_t)j*64;
  int tid = threadIdx.x;
  int ch = tid & 15, r0 = tid >> 4;
  #pragma unroll
  for (int p = 0; p < 4; ++p){
    int r = r0 + p*16;
    int rr = (r < rmax) ? r : 0;
    int sc = ch ^ (r & 7);
    *(uint4*)(&xs[r*128 + sc*8]) = *(const uint4*)(Xb + (row0 + rr)*H_ + ch*8);
    *(uint4*)(&ws[0][r*128 + sc*8]) = *(const uint4*)(Wt + (size_t)r*H_ + ch*8);
  }
  __syncthreads();
  int w = tid >> 6, l = tid & 63;
  int lr = l & 15, q = l >> 4;
  int arow = w*16 + lr;
  bf16x8 afr[4];
  #pragma unroll
  for (int kf = 0; kf < 4; ++kf){
    int bch = kf*4 + q;
    afr[kf] = *(const bf16x8*)(&xs[arow*128 + (bch ^ (arow & 7))*8]);
  }
  #pragma unroll
  for (int cbk = 0; cbk < 8; ++cbk){
    int cur = cbk & 1;
    if (cbk < 7){
      #pragma unroll
      for (int p = 0; p < 4; ++p){
        int r = r0 + p*16;
        int sc = ch ^ (r & 7);
        *(uint4*)(&ws[cur^1][r*128 + sc*8]) =
            *(const uint4*)(Wt + (size_t)((cbk+1)*64 + r)*H_ + ch*8);
      }
    }
    f32x4 z = {0.f, 0.f, 0.f, 0.f};
    f32x4 acc[4] = {z, z, z, z};
    #pragma unroll
    for (int kf = 0; kf < 4; ++kf){
      int bch = kf*4 + q;
      #pragma unroll
      for (int cf = 0; cf < 4; ++cf){
        int brow = cf*16 + lr;
        bf16x8 bfr = *(const bf16x8*)(&ws[cur][brow*128 + (bch ^ (brow & 7))*8]);
        acc[cf] = __builtin_amdgcn_mfma_f32_16x16x32_bf16(afr[kf], bfr, acc[cf], 0, 0, 0);
      }
    }
    #pragma unroll
    for (int cf = 0; cf < 4; ++cf){
      #pragma unroll
      for (int rg = 0; rg < 4; ++rg){
        int rloc = w*16 + q*4 + rg;
        if (rloc < rmax){
          int col = cbk*64 + cf*16 + lr;
          Hb[(row0 + rloc)*HH_ + col] = f2b(acc[cf][rg]);
        }
      }
    }
    __syncthreads();
  }
}

// ---- aggregate: long phase A + pk phase B + XCD swizzle; epilogue fuses LN+ReLU+logits ----
template<bool FINAL>
__global__ __launch_bounds__(256) void k_aggregate(const unsigned short* __restrict__ Hb,
    const float* __restrict__ es, const float* __restrict__ ed,
    const int* __restrict__ off, const int* __restrict__ csr,
    const float* __restrict__ bias,
    const float* __restrict__ wasN, const float* __restrict__ wadN,
    const float* __restrict__ lng, const float* __restrict__ lnb,
    float* __restrict__ Yout, unsigned short* __restrict__ Xbout,
    float* __restrict__ esN, float* __restrict__ edN){
  int idx = blockIdx.x;
  int b = (idx & 7) >> 1;                       // graph -> XCD pair {2b, 2b+1}
  int j = ((idx >> 3) << 1) | (idx & 1);        // block within graph [0,2500)
  int lane = threadIdx.x & 63;
  int t = j*4 + (threadIdx.x >> 6);
  int gw = b*N_ + t;
  const float4 edv = *(const float4*)(ed + (size_t)gw*4);
  int start = off[b*(N_+1) + t];
  int deg = off[b*(N_+1) + t + 1] - start;
  const int* lst = csr + (size_t)b*E_ + start;

  // phase A: online softmax stats (long form — staggers waves, hides phase-B ramp)
  float m0=-1e30f, m1=-1e30f, m2=-1e30f, m3=-1e30f;
  float s0=0.f, s1=0.f, s2=0.f, s3=0.f;
  for (int i = lane; i <= deg; i += 64){
    int srcn = (i < deg) ? lst[i] : t;
    float4 ev = *(const float4*)(es + (size_t)(b*N_ + srcn)*4);
    float e0 = lrelu(ev.x + edv.x);
    float e1 = lrelu(ev.y + edv.y);
    float e2 = lrelu(ev.z + edv.z);
    float e3 = lrelu(ev.w + edv.w);
    float nm;
    nm = fmaxf(m0, e0); s0 = s0*__expf(m0-nm) + __expf(e0-nm); m0 = nm;
    nm = fmaxf(m1, e1); s1 = s1*__expf(m1-nm) + __expf(e1-nm); m1 = nm;
    nm = fmaxf(m2, e2); s2 = s2*__expf(m2-nm) + __expf(e2-nm); m2 = nm;
    nm = fmaxf(m3, e3); s3 = s3*__expf(m3-nm) + __expf(e3-nm); m3 = nm;
  }
  #pragma unroll
  for (int d = 1; d < 64; d <<= 1){
    float om, os, nm;
    om = __shfl_xor(m0, d); os = __shfl_xor(s0, d); nm = fmaxf(m0, om);
    s0 = s0*__expf(m0-nm) + os*__expf(om-nm); m0 = nm;
    om = __shfl_xor(m1, d); os = __shfl_xor(s1, d); nm = fmaxf(m1, om);
    s1 = s1*__expf(m1-nm) + os*__expf(om-nm); m1 = nm;
    om = __shfl_xor(m2, d); os = __shfl_xor(s2, d); nm = fmaxf(m2, om);
    s2 = s2*__expf(m2-nm) + os*__expf(om-nm); m2 = nm;
    om = __shfl_xor(m3, d); os = __shfl_xor(s3, d); nm = fmaxf(m3, om);
    s3 = s3*__expf(m3-nm) + os*__expf(om-nm); m3 = nm;
  }

  // phase B: weighted sum; alpha = exp(e - Lh), Lh = m + log(S)
  int head = lane >> 4;
  float mh, sh, edh;
  if      (head == 0){ mh = m0; sh = s0; edh = edv.x; }
  else if (head == 1){ mh = m1; sh = s1; edh = edv.y; }
  else if (head == 2){ mh = m2; sh = s2; edh = edv.z; }
  else               { mh = m3; sh = s3; edh = edv.w; }
  float Lh = mh + __logf(sh);
  int cb = head*H_ + (lane & 15)*8;
  const unsigned short* hbase = Hb + (size_t)b*N_*HH_;
  const float* esb = es + (size_t)b*N_*4;
  f32x2 zz = {0.f, 0.f};
  f32x2 ac[4] = {zz, zz, zz, zz};
  int total = deg + 1;    // + implicit self-loop
  int i = 0;
  for (; i + 1 < total; i += 2){
    int sA = lst[i];                       // i < deg guaranteed
    int sB = (i + 1 < deg) ? lst[i+1] : t;
    float eA = esb[(size_t)sA*4 + head];
    float eB = esb[(size_t)sB*4 + head];
    uint4 hA = *(const uint4*)(hbase + (size_t)sA*HH_ + cb);
    uint4 hB = *(const uint4*)(hbase + (size_t)sB*HH_ + cb);
    float aA = __expf(lrelu(eA + edh) - Lh);
    float aB = __expf(lrelu(eB + edh) - Lh);
    acc_row(ac, aA, hA);
    acc_row(ac, aB, hB);
  }
  if (i < total){
    int sA = (i < deg) ? lst[i] : t;
    float eA = esb[(size_t)sA*4 + head];
    uint4 hA = *(const uint4*)(hbase + (size_t)sA*HH_ + cb);
    float aA = __expf(lrelu(eA + edh) - Lh);
    acc_row(ac, aA, hA);
  }
  // head mean: after this reduce EVERY lane holds the full sums for channels (lane&15)*8..+7
  float a[8] = {ac[0].x, ac[0].y, ac[1].x, ac[1].y, ac[2].x, ac[2].y, ac[3].x, ac[3].y};
  #pragma unroll
  for (int d = 16; d < 64; d <<= 1)
    #pragma unroll
    for (int j2 = 0; j2 < 8; j2++) a[j2] += __shfl_xor(a[j2], d);

  int c = (lane & 15)*8;
  if (FINAL){
    if (lane < 16){
      float4 o0 = make_float4(0.25f*a[0]+bias[c+0], 0.25f*a[1]+bias[c+1],
                              0.25f*a[2]+bias[c+2], 0.25f*a[3]+bias[c+3]);
      float4 o1 = make_float4(0.25f*a[4]+bias[c+4], 0.25f*a[5]+bias[c+5],
                              0.25f*a[6]+bias[c+6], 0.25f*a[7]+bias[c+7]);
      *(float4*)(Yout + (size_t)gw*H_ + c)     = o0;
      *(float4*)(Yout + (size_t)gw*H_ + c + 4) = o1;
    }
  } else {
    // fused LN+ReLU+next-layer-logits, all in registers (no LDS, no barrier):
    // each 16-lane group reduces over the full 128-ch row (identical data per group).
    float o[8];
    #pragma unroll
    for (int j2 = 0; j2 < 8; j2++) o[j2] = 0.25f*a[j2] + bias[c+j2];
    float ss = 0.f;
    #pragma unroll
    for (int j2 = 0; j2 < 8; j2++) ss += o[j2];
    #pragma unroll
    for (int d = 1; d < 16; d <<= 1) ss += __shfl_xor(ss, d);
    float mu = ss * (1.f/H_);
    float vv = 0.f;
    #pragma unroll
    for (int j2 = 0; j2 < 8; j2++){ float dx = o[j2]-mu; vv += dx*dx; }
    #pragma unroll
    for (int d = 1; d < 16; d <<= 1) vv += __shfl_xor(vv, d);
    float inv = rsqrtf(vv*(1.f/H_) + 1e-5f);
    float4 g0 = *(const float4*)(lng + c), g1 = *(const float4*)(lng + c + 4);
    float4 b0 = *(const float4*)(lnb + c), b1 = *(const float4*)(lnb + c + 4);
    float gg[8] = {g0.x,g0.y,g0.z,g0.w,g1.x,g1.y,g1.z,g1.w};
    float bb[8] = {b0.x,b0.y,b0.z,b0.w,b1.x,b1.y,b1.z,b1.w};
    float oo[8];
    #pragma unroll
    for (int j2 = 0; j2 < 8; j2++) oo[j2] = fmaxf((o[j2]-mu)*inv*gg[j2] + bb[j2], 0.f);
    if (lane < 16){
      uint4 up;
      up.x = ((unsigned int)f2b(oo[1]) << 16) | f2b(oo[0]);
      up.y = ((unsigned int)f2b(oo[3]) << 16) | f2b(oo[2]);
      up.z = ((unsigned int)f2b(oo[5]) << 16) | f2b(oo[4]);
      up.w = ((unsigned int)f2b(oo[7]) << 16) | f2b(oo[6]);
      *(uint4*)(Xbout + (size_t)gw*H_ + lane*8) = up;
    }
    // next-layer logits: lane (head, channels c..c+7) -> partial dot, reduce over 16 lanes
    float pe = 0.f, pd = 0.f;
    #pragma unroll
    for (int j2 = 0; j2 < 8; j2++){
      pe += oo[j2] * wasN[(c + j2)*4 + head];
      pd += oo[j2] * wadN[(c + j2)*4 + head];
    }
    #pragma unroll
    for (int d = 1; d < 16; d <<= 1){ pe += __shfl_xor(pe, d); pd += __shfl_xor(pd, d); }
    if ((lane & 15) == 0){
      esN[(size_t)gw*4 + head] = pe;
      edN[(size_t)gw*4 + head] = pd;
    }
  }
}

extern "C" void kernel_launch(void* const* d_in, const int* in_sizes, int n_in,
                              void* d_out, int out_size, void* d_ws, size_t ws_size,
                              hipStream_t stream){
  const float* x0   = (const float*)d_in[0];
  const int*   srcI = (const int*)d_in[1];
  const int*   tgtI = (const int*)d_in[2];
  const float* Wl[3]  = {(const float*)d_in[3], (const float*)d_in[7],  (const float*)d_in[11]};
  const float* asl[3] = {(const float*)d_in[4], (const float*)d_in[8],  (const float*)d_in[12]};
  const float* adl[3] = {(const float*)d_in[5], (const float*)d_in[9],  (const float*)d_in[13]};
  const float* bl[3]  = {(const float*)d_in[6], (const float*)d_in[10], (const float*)d_in[14]};
  const float* lng[2] = {(const float*)d_in[15], (const float*)d_in[17]};
  const float* lnb[2] = {(const float*)d_in[16], (const float*)d_in[18]};

  char* p = (char*)d_ws;
  auto carve = [&](size_t bytes) -> void* {
    void* r = (void*)p; p += (bytes + 255) & ~(size_t)255; return r;
  };
  int*   off    = (int*)carve((size_t)B_*(N_+1)*4);
  int*   cnt    = (int*)carve((size_t)B_*N_*4);
  int*   cursor = (int*)carve((size_t)B_*N_*4);
  int*   csr    = (int*)carve((size_t)B_*E_*4);
  float* es2[2] = {(float*)carve((size_t)NROWS*4*4), (float*)carve((size_t)NROWS*4*4)};
  float* ed2[2] = {(float*)carve((size_t)NROWS*4*4), (float*)carve((size_t)NROWS*4*4)};
  float* wasA   = (float*)carve((size_t)3*HH_*4);
  float* wadA   = (float*)carve((size_t)3*HH_*4);
  unsigned short* wtA  = (unsigned short*)carve((size_t)3*HH_*H_*2);
  unsigned short* hbuf = (unsigned short*)carve((size_t)NROWS*HH_*2);
  unsigned short* xbf  = (unsigned short*)carve((size_t)NROWS*H_*2);

  hipMemsetAsync(cnt, 0, (size_t)B_*N_*4, stream);
  k_count  <<<dim3(E_/256, B_), 256, 0, stream>>>(tgtI, cnt);
  k_scan   <<<B_, 1024, 0, stream>>>(cnt, off, cursor);
  k_scatter<<<dim3(E_/256, B_), 256, 0, stream>>>(srcI, tgtI, cursor, csr);
  k_prep   <<<dim3(258, 3), 256, 0, stream>>>(Wl[0], Wl[1], Wl[2],
                                              asl[0], asl[1], asl[2],
                                              adl[0], adl[1], adl[2],
                                              wasA, wadA, wtA);
  k_cast_logits<<<NROWS/4, 256, 0, stream>>>(x0, wasA, wadA, xbf, es2[0], ed2[0]);

  for (int l = 0; l < 3; ++l){
    k_gemm_mfma<<<632, 256, 0, stream>>>(xbf, wtA + (size_t)l*HH_*H_, hbuf);
    int cur = l & 1, nxt = cur ^ 1;
    if (l < 2){
      k_aggregate<false><<<NROWS/4, 256, 0, stream>>>(hbuf, es2[cur], ed2[cur], off, csr, bl[l],
          wasA + (size_t)(l+1)*HH_, wadA + (size_t)(l+1)*HH_, lng[l], lnb[l],
          nullptr, xbf, es2[nxt], ed2[nxt]);
    } else {
      k_aggregate<true><<<NROWS/4, 256, 0, stream>>>(hbuf, es2[cur], ed2[cur], off, csr, bl[l],
          nullptr, nullptr, nullptr, nullptr,
          (float*)d_out, nullptr, nullptr, nullptr);
    }
  }
}

// Round 14
// 450.413 us; speedup vs baseline: 1.1090x; 1.1090x over previous
//
#include <hip/hip_runtime.h>
#include <hip/hip_bf16.h>
#include <cstdint>
#include <cstddef>

#define B_ 4
#define N_ 10000
#define E_ 160000
#define H_ 128
#define HEADS_ 4
#define HH_ 512
#define NROWS (B_*N_)

typedef __attribute__((ext_vector_type(8))) short bf16x8;
typedef __attribute__((ext_vector_type(4))) float f32x4;
typedef __attribute__((ext_vector_type(2))) float f32x2;

__device__ __forceinline__ float lrelu(float x){ return x > 0.f ? x : 0.2f*x; }
__device__ __forceinline__ unsigned short f2b(float f){
  unsigned int u = __builtin_bit_cast(unsigned int, f);
  unsigned int r = (u + 0x7fffu + ((u >> 16) & 1u)) >> 16;
  return (unsigned short)r;
}
__device__ __forceinline__ float blo(unsigned int u){ return __builtin_bit_cast(float, u << 16); }
__device__ __forceinline__ float bhi(unsigned int u){ return __builtin_bit_cast(float, u & 0xffff0000u); }

__device__ __forceinline__ void acc_row(f32x2* ac, float al, uint4 h){
  f32x2 v = {al, al};
  ac[0] += v * (f32x2){blo(h.x), bhi(h.x)};
  ac[1] += v * (f32x2){blo(h.y), bhi(h.y)};
  ac[2] += v * (f32x2){blo(h.z), bhi(h.z)};
  ac[3] += v * (f32x2){blo(h.w), bhi(h.w)};
}

// ---------------- CSR build ----------------
__global__ void k_count(const int* __restrict__ tgt, int* __restrict__ cnt){
  int e = blockIdx.x*blockDim.x + threadIdx.x;
  int b = blockIdx.y;
  int t = tgt[(size_t)b*E_ + e];
  atomicAdd(&cnt[b*N_ + t], 1);
}

__global__ void k_scan(const int* __restrict__ cnt, int* __restrict__ off, int* __restrict__ cursor){
  int b = blockIdx.x;
  __shared__ int wsum[16];
  __shared__ int carry_s;
  int lane = threadIdx.x & 63, wid = threadIdx.x >> 6;
  if (threadIdx.x == 0){ carry_s = 0; off[b*(N_+1)] = 0; }
  __syncthreads();
  for (int base = 0; base < N_; base += 1024){
    int i = base + threadIdx.x;
    int v = (i < N_) ? cnt[b*N_ + i] : 0;
    int x = v;
    #pragma unroll
    for (int d = 1; d < 64; d <<= 1){
      int y = __shfl_up(x, d);
      if (lane >= d) x += y;
    }
    if (lane == 63) wsum[wid] = x;
    __syncthreads();
    if (wid == 0 && lane < 16){
      int w = wsum[lane];
      #pragma unroll
      for (int d = 1; d < 16; d <<= 1){
        int y = __shfl_up(w, d, 16);
        if (lane >= d) w += y;
      }
      wsum[lane] = w;
    }
    __syncthreads();
    int excl = (wid ? wsum[wid-1] : 0) + carry_s;
    if (i < N_){
      int inc = x + excl;
      off[b*(N_+1) + i + 1] = inc;
      cursor[b*N_ + i] = inc - v;
    }
    __syncthreads();
    if (threadIdx.x == 0) carry_s += wsum[15];
    __syncthreads();
  }
}

__global__ void k_scatter(const int* __restrict__ src, const int* __restrict__ tgt,
                          int* __restrict__ cursor, int* __restrict__ csr){
  int e = blockIdx.x*blockDim.x + threadIdx.x;
  int b = blockIdx.y;
  int t = tgt[(size_t)b*E_ + e];
  int pos = atomicAdd(&cursor[b*N_ + t], 1);
  csr[(size_t)b*E_ + pos] = src[(size_t)b*E_ + e];
}

// ---------------- prep: Wa tables + W transpose/cast, all 3 layers ----------------
__global__ void k_prep(const float* __restrict__ W0, const float* __restrict__ W1, const float* __restrict__ W2,
                       const float* __restrict__ as0, const float* __restrict__ as1, const float* __restrict__ as2,
                       const float* __restrict__ ad0, const float* __restrict__ ad1, const float* __restrict__ ad2,
                       float* __restrict__ wasA, float* __restrict__ wadA, unsigned short* __restrict__ wtA){
  int l = blockIdx.y;
  const float* W   = (l==0)?W0:(l==1)?W1:W2;
  const float* asp = (l==0)?as0:(l==1)?as1:as2;
  const float* adp = (l==0)?ad0:(l==1)?ad1:ad2;
  if (blockIdx.x < 256){
    int i = blockIdx.x*256 + threadIdx.x;     // i = c*H_ + k
    int c = i >> 7, k = i & 127;
    wtA[(size_t)l*HH_*H_ + i] = f2b(W[(size_t)k*HH_ + c]);
  } else {
    int j = (blockIdx.x - 256)*256 + threadIdx.x;   // j = k*4 + h
    if (j < H_*HEADS_){
      int k = j >> 2, h = j & 3;
      const float* wrow = W + (size_t)k*HH_ + h*H_;
      const float* asr = asp + h*H_;
      const float* adr = adp + h*H_;
      float ss = 0.f, sd = 0.f;
      for (int c = 0; c < H_; ++c){ float w = wrow[c]; ss += w*asr[c]; sd += w*adr[c]; }
      wasA[l*HH_ + j] = ss; wadA[l*HH_ + j] = sd;
    }
  }
}

// ---------------- layer-1: cast x->bf16 + logits (one wave per row) ----------------
__global__ __launch_bounds__(256) void k_cast_logits(const float* __restrict__ X,
    const float* __restrict__ was, const float* __restrict__ wad,
    unsigned short* __restrict__ Xb, float* __restrict__ es, float* __restrict__ ed){
  int gw = (blockIdx.x*blockDim.x + threadIdx.x) >> 6;
  int lane = threadIdx.x & 63;
  float2 v = *(const float2*)(X + (size_t)gw*H_ + lane*2);
  unsigned int o = ((unsigned int)f2b(v.y) << 16) | (unsigned int)f2b(v.x);
  *(unsigned int*)(Xb + (size_t)gw*H_ + lane*2) = o;
  int c = lane*2;
  const f32x4* w4 = (const f32x4*)was;
  const f32x4* d4 = (const f32x4*)wad;
  f32x4 se = v.x*w4[c] + v.y*w4[c+1];
  f32x4 de = v.x*d4[c] + v.y*d4[c+1];
  #pragma unroll
  for (int d = 1; d < 64; d <<= 1){
    se.x += __shfl_xor(se.x,d); se.y += __shfl_xor(se.y,d);
    se.z += __shfl_xor(se.z,d); se.w += __shfl_xor(se.w,d);
    de.x += __shfl_xor(de.x,d); de.y += __shfl_xor(de.y,d);
    de.z += __shfl_xor(de.z,d); de.w += __shfl_xor(de.w,d);
  }
  if (lane == 0){
    *(float4*)(es + (size_t)gw*4) = make_float4(se.x, se.y, se.z, se.w);
    *(float4*)(ed + (size_t)gw*4) = make_float4(de.x, de.y, de.z, de.w);
  }
}

// ---- h = x @ W: one block = 64 rows x all 512 cols; X staged once, Wt dbuf-looped.
//      C written via LDS re-stage (xs reused) for coalesced dwordx4 stores. ----
__global__ __launch_bounds__(256) void k_gemm_mfma(const unsigned short* __restrict__ Xb,
    const unsigned short* __restrict__ Wt, unsigned short* __restrict__ Hb){
  __shared__ unsigned short xs[64*128];        // 16 KB; reused as C-staging [64][72]
  __shared__ unsigned short ws[2][64*128];     // 32 KB double buffer
  int idx = blockIdx.x;
  int g = (idx & 7) >> 1;
  int j = ((idx >> 3) << 1) | (idx & 1);
  if (j >= 157) return;
  int rmax = N_ - j*64; if (rmax > 64) rmax = 64;
  size_t row0 = (size_t)g*N_ + (size_t)j*64;
  int tid = threadIdx.x;
  int ch = tid & 15, r0 = tid >> 4;
  #pragma unroll
  for (int p = 0; p < 4; ++p){
    int r = r0 + p*16;
    int rr = (r < rmax) ? r : 0;
    int sc = ch ^ (r & 7);
    *(uint4*)(&xs[r*128 + sc*8]) = *(const uint4*)(Xb + (row0 + rr)*H_ + ch*8);
    *(uint4*)(&ws[0][r*128 + sc*8]) = *(const uint4*)(Wt + (size_t)r*H_ + ch*8);
  }
  __syncthreads();
  int w = tid >> 6, l = tid & 63;
  int lr = l & 15, q = l >> 4;
  int arow = w*16 + lr;
  bf16x8 afr[4];
  #pragma unroll
  for (int kf = 0; kf < 4; ++kf){
    int bch = kf*4 + q;
    afr[kf] = *(const bf16x8*)(&xs[arow*128 + (bch ^ (arow & 7))*8]);
  }
  __syncthreads();                 // xs free -> C staging buffer
  unsigned short* cs = xs;         // [64][72] padded (144 B rows: 16B-aligned)
  #pragma unroll
  for (int cbk = 0; cbk < 8; ++cbk){
    int cur = cbk & 1;
    if (cbk < 7){
      #pragma unroll
      for (int p = 0; p < 4; ++p){
        int r = r0 + p*16;
        int sc = ch ^ (r & 7);
        *(uint4*)(&ws[cur^1][r*128 + sc*8]) =
            *(const uint4*)(Wt + (size_t)((cbk+1)*64 + r)*H_ + ch*8);
      }
    }
    f32x4 z = {0.f, 0.f, 0.f, 0.f};
    f32x4 acc[4] = {z, z, z, z};
    #pragma unroll
    for (int kf = 0; kf < 4; ++kf){
      int bch = kf*4 + q;
      #pragma unroll
      for (int cf = 0; cf < 4; ++cf){
        int brow = cf*16 + lr;
        bf16x8 bfr = *(const bf16x8*)(&ws[cur][brow*128 + (bch ^ (brow & 7))*8]);
        acc[cf] = __builtin_amdgcn_mfma_f32_16x16x32_bf16(afr[kf], bfr, acc[cf], 0, 0, 0);
      }
    }
    // stage C tile (64x64 bf16) into cs
    #pragma unroll
    for (int cf = 0; cf < 4; ++cf)
      #pragma unroll
      for (int rg = 0; rg < 4; ++rg)
        cs[(w*16 + q*4 + rg)*72 + cf*16 + lr] = f2b(acc[cf][rg]);
    __syncthreads();
    // coalesced store: 64 rows x 128 B; 512 chunks of 16 B, 2 per thread
    #pragma unroll
    for (int p = 0; p < 2; ++p){
      int k = tid + p*256;
      int r = k >> 3, c8 = k & 7;
      if (r < rmax){
        uint4 v = *(const uint4*)(&cs[r*72 + c8*8]);
        *(uint4*)(Hb + (row0 + r)*HH_ + cbk*64 + c8*8) = v;
      }
    }
    __syncthreads();
  }
}

// ---------------- aggregate: long phase A + pk phase B + XCD swizzle (R12 frozen) ----------------
__global__ __launch_bounds__(256) void k_aggregate(const unsigned short* __restrict__ Hb,
    const float* __restrict__ es, const float* __restrict__ ed,
    const int* __restrict__ off, const int* __restrict__ csr,
    const float* __restrict__ bias, float* __restrict__ Y){
  int idx = blockIdx.x;
  int b = (idx & 7) >> 1;                       // graph -> XCD pair {2b, 2b+1}
  int j = ((idx >> 3) << 1) | (idx & 1);        // block within graph [0,2500)
  int lane = threadIdx.x & 63;
  int t = j*4 + (threadIdx.x >> 6);
  int gw = b*N_ + t;
  const float4 edv = *(const float4*)(ed + (size_t)gw*4);
  int start = off[b*(N_+1) + t];
  int deg = off[b*(N_+1) + t + 1] - start;
  const int* lst = csr + (size_t)b*E_ + start;

  // phase A: online softmax stats (long form — staggers waves, hides phase-B ramp)
  float m0=-1e30f, m1=-1e30f, m2=-1e30f, m3=-1e30f;
  float s0=0.f, s1=0.f, s2=0.f, s3=0.f;
  for (int i = lane; i <= deg; i += 64){
    int srcn = (i < deg) ? lst[i] : t;
    float4 ev = *(const float4*)(es + (size_t)(b*N_ + srcn)*4);
    float e0 = lrelu(ev.x + edv.x);
    float e1 = lrelu(ev.y + edv.y);
    float e2 = lrelu(ev.z + edv.z);
    float e3 = lrelu(ev.w + edv.w);
    float nm;
    nm = fmaxf(m0, e0); s0 = s0*__expf(m0-nm) + __expf(e0-nm); m0 = nm;
    nm = fmaxf(m1, e1); s1 = s1*__expf(m1-nm) + __expf(e1-nm); m1 = nm;
    nm = fmaxf(m2, e2); s2 = s2*__expf(m2-nm) + __expf(e2-nm); m2 = nm;
    nm = fmaxf(m3, e3); s3 = s3*__expf(m3-nm) + __expf(e3-nm); m3 = nm;
  }
  #pragma unroll
  for (int d = 1; d < 64; d <<= 1){
    float om, os, nm;
    om = __shfl_xor(m0, d); os = __shfl_xor(s0, d); nm = fmaxf(m0, om);
    s0 = s0*__expf(m0-nm) + os*__expf(om-nm); m0 = nm;
    om = __shfl_xor(m1, d); os = __shfl_xor(s1, d); nm = fmaxf(m1, om);
    s1 = s1*__expf(m1-nm) + os*__expf(om-nm); m1 = nm;
    om = __shfl_xor(m2, d); os = __shfl_xor(s2, d); nm = fmaxf(m2, om);
    s2 = s2*__expf(m2-nm) + os*__expf(om-nm); m2 = nm;
    om = __shfl_xor(m3, d); os = __shfl_xor(s3, d); nm = fmaxf(m3, om);
    s3 = s3*__expf(m3-nm) + os*__expf(om-nm); m3 = nm;
  }

  // phase B: weighted sum; alpha = exp(e - Lh), Lh = m + log(S)
  int head = lane >> 4;
  float mh, sh, edh;
  if      (head == 0){ mh = m0; sh = s0; edh = edv.x; }
  else if (head == 1){ mh = m1; sh = s1; edh = edv.y; }
  else if (head == 2){ mh = m2; sh = s2; edh = edv.z; }
  else               { mh = m3; sh = s3; edh = edv.w; }
  float Lh = mh + __logf(sh);
  int cb = head*H_ + (lane & 15)*8;
  const unsigned short* hbase = Hb + (size_t)b*N_*HH_;
  const float* esb = es + (size_t)b*N_*4;
  f32x2 zz = {0.f, 0.f};
  f32x2 ac[4] = {zz, zz, zz, zz};
  int total = deg + 1;    // + implicit self-loop
  int i = 0;
  for (; i + 1 < total; i += 2){
    int sA = lst[i];                       // i < deg guaranteed
    int sB = (i + 1 < deg) ? lst[i+1] : t;
    float eA = esb[(size_t)sA*4 + head];
    float eB = esb[(size_t)sB*4 + head];
    uint4 hA = *(const uint4*)(hbase + (size_t)sA*HH_ + cb);
    uint4 hB = *(const uint4*)(hbase + (size_t)sB*HH_ + cb);
    float aA = __expf(lrelu(eA + edh) - Lh);
    float aB = __expf(lrelu(eB + edh) - Lh);
    acc_row(ac, aA, hA);
    acc_row(ac, aB, hB);
  }
  if (i < total){
    int sA = (i < deg) ? lst[i] : t;
    float eA = esb[(size_t)sA*4 + head];
    uint4 hA = *(const uint4*)(hbase + (size_t)sA*HH_ + cb);
    float aA = __expf(lrelu(eA + edh) - Lh);
    acc_row(ac, aA, hA);
  }
  // head mean
  float a[8] = {ac[0].x, ac[0].y, ac[1].x, ac[1].y, ac[2].x, ac[2].y, ac[3].x, ac[3].y};
  #pragma unroll
  for (int d = 16; d < 64; d <<= 1)
    #pragma unroll
    for (int j2 = 0; j2 < 8; j2++) a[j2] += __shfl_xor(a[j2], d);
  if (lane < 16){
    int c = lane*8;
    float4 o0 = make_float4(0.25f*a[0]+bias[c+0], 0.25f*a[1]+bias[c+1],
                            0.25f*a[2]+bias[c+2], 0.25f*a[3]+bias[c+3]);
    float4 o1 = make_float4(0.25f*a[4]+bias[c+4], 0.25f*a[5]+bias[c+5],
                            0.25f*a[6]+bias[c+6], 0.25f*a[7]+bias[c+7]);
    *(float4*)(Y + (size_t)gw*H_ + c)     = o0;
    *(float4*)(Y + (size_t)gw*H_ + c + 4) = o1;
  }
}

// ---------------- fused LayerNorm+ReLU + next-layer logits (one wave per row) ----------------
__global__ __launch_bounds__(256) void k_lnrelu_logits(const float* __restrict__ Y,
    const float* __restrict__ g, const float* __restrict__ bb,
    const float* __restrict__ was, const float* __restrict__ wad,
    unsigned short* __restrict__ Xb, float* __restrict__ es, float* __restrict__ ed){
  int gw = (blockIdx.x*blockDim.x + threadIdx.x) >> 6;
  int lane = threadIdx.x & 63;
  float2 v = *(const float2*)(Y + (size_t)gw*H_ + lane*2);
  float sum = v.x + v.y;
  #pragma unroll
  for (int d = 1; d < 64; d <<= 1) sum += __shfl_xor(sum, d);
  float mu = sum * (1.f/H_);
  float dx = v.x - mu, dy = v.y - mu;
  float vs = dx*dx + dy*dy;
  #pragma unroll
  for (int d = 1; d < 64; d <<= 1) vs += __shfl_xor(vs, d);
  float inv = rsqrtf(vs*(1.f/H_) + 1e-5f);
  float2 gv = *(const float2*)(g + lane*2);
  float2 bv = *(const float2*)(bb + lane*2);
  float ox = fmaxf(dx*inv*gv.x + bv.x, 0.f);
  float oy = fmaxf(dy*inv*gv.y + bv.y, 0.f);
  unsigned int o = ((unsigned int)f2b(oy) << 16) | (unsigned int)f2b(ox);
  *(unsigned int*)(Xb + (size_t)gw*H_ + lane*2) = o;
  // logits for next layer from in-register row
  int c = lane*2;
  const f32x4* w4 = (const f32x4*)was;
  const f32x4* d4 = (const f32x4*)wad;
  f32x4 se = ox*w4[c] + oy*w4[c+1];
  f32x4 de = ox*d4[c] + oy*d4[c+1];
  #pragma unroll
  for (int d = 1; d < 64; d <<= 1){
    se.x += __shfl_xor(se.x,d); se.y += __shfl_xor(se.y,d);
    se.z += __shfl_xor(se.z,d); se.w += __shfl_xor(se.w,d);
    de.x += __shfl_xor(de.x,d); de.y += __shfl_xor(de.y,d);
    de.z += __shfl_xor(de.z,d); de.w += __shfl_xor(de.w,d);
  }
  if (lane == 0){
    *(float4*)(es + (size_t)gw*4) = make_float4(se.x, se.y, se.z, se.w);
    *(float4*)(ed + (size_t)gw*4) = make_float4(de.x, de.y, de.z, de.w);
  }
}

extern "C" void kernel_launch(void* const* d_in, const int* in_sizes, int n_in,
                              void* d_out, int out_size, void* d_ws, size_t ws_size,
                              hipStream_t stream){
  const float* x0   = (const float*)d_in[0];
  const int*   srcI = (const int*)d_in[1];
  const int*   tgtI = (const int*)d_in[2];
  const float* Wl[3]  = {(const float*)d_in[3], (const float*)d_in[7],  (const float*)d_in[11]};
  const float* asl[3] = {(const float*)d_in[4], (const float*)d_in[8],  (const float*)d_in[12]};
  const float* adl[3] = {(const float*)d_in[5], (const float*)d_in[9],  (const float*)d_in[13]};
  const float* bl[3]  = {(const float*)d_in[6], (const float*)d_in[10], (const float*)d_in[14]};
  const float* lng[2] = {(const float*)d_in[15], (const float*)d_in[17]};
  const float* lnb[2] = {(const float*)d_in[16], (const float*)d_in[18]};

  char* p = (char*)d_ws;
  auto carve = [&](size_t bytes) -> void* {
    void* r = (void*)p; p += (bytes + 255) & ~(size_t)255; return r;
  };
  int*   off    = (int*)carve((size_t)B_*(N_+1)*4);
  int*   cnt    = (int*)carve((size_t)B_*N_*4);
  int*   cursor = (int*)carve((size_t)B_*N_*4);
  int*   csr    = (int*)carve((size_t)B_*E_*4);
  float* es     = (float*)carve((size_t)NROWS*4*4);
  float* ed     = (float*)carve((size_t)NROWS*4*4);
  float* wasA   = (float*)carve((size_t)3*HH_*4);
  float* wadA   = (float*)carve((size_t)3*HH_*4);
  unsigned short* wtA  = (unsigned short*)carve((size_t)3*HH_*H_*2);
  unsigned short* hbuf = (unsigned short*)carve((size_t)NROWS*HH_*2);
  unsigned short* xbf  = (unsigned short*)carve((size_t)NROWS*H_*2);
  float* tbuf   = (float*)carve((size_t)NROWS*H_*4);

  hipMemsetAsync(cnt, 0, (size_t)B_*N_*4, stream);
  k_count  <<<dim3(E_/256, B_), 256, 0, stream>>>(tgtI, cnt);
  k_scan   <<<B_, 1024, 0, stream>>>(cnt, off, cursor);
  k_scatter<<<dim3(E_/256, B_), 256, 0, stream>>>(srcI, tgtI, cursor, csr);
  k_prep   <<<dim3(258, 3), 256, 0, stream>>>(Wl[0], Wl[1], Wl[2],
                                              asl[0], asl[1], asl[2],
                                              adl[0], adl[1], adl[2],
                                              wasA, wadA, wtA);
  k_cast_logits<<<NROWS/4, 256, 0, stream>>>(x0, wasA, wadA, xbf, es, ed);

  for (int l = 0; l < 3; ++l){
    k_gemm_mfma<<<632, 256, 0, stream>>>(xbf, wtA + (size_t)l*HH_*H_, hbuf);
    float* yout = (l == 2) ? (float*)d_out : tbuf;
    k_aggregate<<<NROWS/4, 256, 0, stream>>>(hbuf, es, ed, off, csr, bl[l], yout);
    if (l < 2){
      k_lnrelu_logits<<<NROWS/4, 256, 0, stream>>>(tbuf, lng[l], lnb[l],
          wasA + (size_t)(l+1)*HH_, wadA + (size_t)(l+1)*HH_, xbf, es, ed);
    }
  }
}

// Round 15
// 442.144 us; speedup vs baseline: 1.1298x; 1.0187x over previous
//
#include <hip/hip_runtime.h>
#include <hip/hip_bf16.h>
#include <cstdint>
#include <cstddef>

#define B_ 4
#define N_ 10000
#define E_ 160000
#define H_ 128
#define HEADS_ 4
#define HH_ 512
#define NROWS (B_*N_)

typedef __attribute__((ext_vector_type(8))) short bf16x8;
typedef __attribute__((ext_vector_type(4))) float f32x4;
typedef __attribute__((ext_vector_type(2))) float f32x2;

__device__ __forceinline__ float lrelu(float x){ return x > 0.f ? x : 0.2f*x; }
__device__ __forceinline__ unsigned short f2b(float f){
  unsigned int u = __builtin_bit_cast(unsigned int, f);
  unsigned int r = (u + 0x7fffu + ((u >> 16) & 1u)) >> 16;
  return (unsigned short)r;
}
__device__ __forceinline__ float blo(unsigned int u){ return __builtin_bit_cast(float, u << 16); }
__device__ __forceinline__ float bhi(unsigned int u){ return __builtin_bit_cast(float, u & 0xffff0000u); }

__device__ __forceinline__ void acc_row(f32x2* ac, float al, uint4 h){
  f32x2 v = {al, al};
  ac[0] += v * (f32x2){blo(h.x), bhi(h.x)};
  ac[1] += v * (f32x2){blo(h.y), bhi(h.y)};
  ac[2] += v * (f32x2){blo(h.z), bhi(h.z)};
  ac[3] += v * (f32x2){blo(h.w), bhi(h.w)};
}

// ---- fused setup: [0,2500) edge-count | [2500,3274) prep Wa/Wt | [3274,8274) x->bf16 cast ----
__global__ __launch_bounds__(256) void k_setup(
    const int* __restrict__ tgt, int* __restrict__ cnt,
    const float* __restrict__ W0, const float* __restrict__ W1, const float* __restrict__ W2,
    const float* __restrict__ as0, const float* __restrict__ as1, const float* __restrict__ as2,
    const float* __restrict__ ad0, const float* __restrict__ ad1, const float* __restrict__ ad2,
    float* __restrict__ wasA, float* __restrict__ wadA, unsigned short* __restrict__ wtA,
    const float* __restrict__ X, unsigned short* __restrict__ Xb){
  int blk = blockIdx.x;
  int tid = threadIdx.x;
  if (blk < 2500){
    int b = blk / 625, eb = blk - b*625;
    int e = eb*256 + tid;
    int t = tgt[(size_t)b*E_ + e];
    atomicAdd(&cnt[b*N_ + t], 1);
  } else if (blk < 3274){
    int local = blk - 2500;
    int l = local / 258, px = local - l*258;
    const float* W   = (l==0)?W0:(l==1)?W1:W2;
    const float* asp = (l==0)?as0:(l==1)?as1:as2;
    const float* adp = (l==0)?ad0:(l==1)?ad1:ad2;
    if (px < 256){
      int i = px*256 + tid;                  // i = c*H_ + k
      int c = i >> 7, k = i & 127;
      wtA[(size_t)l*HH_*H_ + i] = f2b(W[(size_t)k*HH_ + c]);
    } else {
      int j = (px - 256)*256 + tid;          // j = k*4 + h
      if (j < H_*HEADS_){
        int k = j >> 2, h = j & 3;
        const float* wrow = W + (size_t)k*HH_ + h*H_;
        const float* asr = asp + h*H_;
        const float* adr = adp + h*H_;
        float ss = 0.f, sd = 0.f;
        for (int c = 0; c < H_; ++c){ float w = wrow[c]; ss += w*asr[c]; sd += w*adr[c]; }
        wasA[l*HH_ + j] = ss; wadA[l*HH_ + j] = sd;
      }
    }
  } else {
    int i = (blk - 3274)*256 + tid;          // float4 index, NROWS*H_/4 total
    float4 v = ((const float4*)X)[i];
    ushort4 o; o.x = f2b(v.x); o.y = f2b(v.y); o.z = f2b(v.z); o.w = f2b(v.w);
    ((ushort4*)Xb)[i] = o;
  }
}

__global__ void k_scan(const int* __restrict__ cnt, int* __restrict__ off, int* __restrict__ cursor){
  int b = blockIdx.x;
  __shared__ int wsum[16];
  __shared__ int carry_s;
  int lane = threadIdx.x & 63, wid = threadIdx.x >> 6;
  if (threadIdx.x == 0){ carry_s = 0; off[b*(N_+1)] = 0; }
  __syncthreads();
  for (int base = 0; base < N_; base += 1024){
    int i = base + threadIdx.x;
    int v = (i < N_) ? cnt[b*N_ + i] : 0;
    int x = v;
    #pragma unroll
    for (int d = 1; d < 64; d <<= 1){
      int y = __shfl_up(x, d);
      if (lane >= d) x += y;
    }
    if (lane == 63) wsum[wid] = x;
    __syncthreads();
    if (wid == 0 && lane < 16){
      int w = wsum[lane];
      #pragma unroll
      for (int d = 1; d < 16; d <<= 1){
        int y = __shfl_up(w, d, 16);
        if (lane >= d) w += y;
      }
      wsum[lane] = w;
    }
    __syncthreads();
    int excl = (wid ? wsum[wid-1] : 0) + carry_s;
    if (i < N_){
      int inc = x + excl;
      off[b*(N_+1) + i + 1] = inc;
      cursor[b*N_ + i] = inc - v;
    }
    __syncthreads();
    if (threadIdx.x == 0) carry_s += wsum[15];
    __syncthreads();
  }
}

// ---- fused: [0,2500) scatter | [2500,12500) layer-1 logits from bf16 x ----
__global__ __launch_bounds__(256) void k_misc(
    const int* __restrict__ src, const int* __restrict__ tgt,
    int* __restrict__ cursor, int* __restrict__ csr,
    const unsigned short* __restrict__ Xb,
    const float* __restrict__ was, const float* __restrict__ wad,
    float* __restrict__ es, float* __restrict__ ed){
  int blk = blockIdx.x;
  int tid = threadIdx.x;
  if (blk < 2500){
    int b = blk / 625, eb = blk - b*625;
    int e = eb*256 + tid;
    int t = tgt[(size_t)b*E_ + e];
    int pos = atomicAdd(&cursor[b*N_ + t], 1);
    csr[(size_t)b*E_ + pos] = src[(size_t)b*E_ + e];
  } else {
    int gw = ((blk - 2500)*256 + tid) >> 6;
    int lane = tid & 63;
    unsigned int u = *(const unsigned int*)(Xb + (size_t)gw*H_ + lane*2);
    float xlo = blo(u), xhi = bhi(u);
    int c = lane*2;
    const f32x4* w4 = (const f32x4*)was;
    const f32x4* d4 = (const f32x4*)wad;
    f32x4 se = xlo*w4[c] + xhi*w4[c+1];
    f32x4 de = xlo*d4[c] + xhi*d4[c+1];
    #pragma unroll
    for (int d = 1; d < 64; d <<= 1){
      se.x += __shfl_xor(se.x,d); se.y += __shfl_xor(se.y,d);
      se.z += __shfl_xor(se.z,d); se.w += __shfl_xor(se.w,d);
      de.x += __shfl_xor(de.x,d); de.y += __shfl_xor(de.y,d);
      de.z += __shfl_xor(de.z,d); de.w += __shfl_xor(de.w,d);
    }
    if (lane == 0){
      *(float4*)(es + (size_t)gw*4) = make_float4(se.x, se.y, se.z, se.w);
      *(float4*)(ed + (size_t)gw*4) = make_float4(de.x, de.y, de.z, de.w);
    }
  }
}

// ---- h = x @ W: one block = 64 rows x 256 cols (colhalf); X staged once, Wt dbuf-looped. ----
__global__ __launch_bounds__(256) void k_gemm_mfma(const unsigned short* __restrict__ Xb,
    const unsigned short* __restrict__ Wt, unsigned short* __restrict__ Hb){
  __shared__ unsigned short xs[64*128];        // 16 KB; reused as C-staging [64][72]
  __shared__ unsigned short ws[2][64*128];     // 32 KB double buffer
  int idx = blockIdx.x;
  int g = (idx & 7) >> 1;                      // graph -> XCD pair {2g,2g+1}
  int colhalf = idx & 1;
  int j = idx >> 3;
  if (j >= 157) return;
  int rmax = N_ - j*64; if (rmax > 64) rmax = 64;
  size_t row0 = (size_t)g*N_ + (size_t)j*64;
  int col0 = colhalf*256;
  int tid = threadIdx.x;
  int ch = tid & 15, r0 = tid >> 4;
  #pragma unroll
  for (int p = 0; p < 4; ++p){
    int r = r0 + p*16;
    int rr = (r < rmax) ? r : 0;
    int sc = ch ^ (r & 7);
    *(uint4*)(&xs[r*128 + sc*8]) = *(const uint4*)(Xb + (row0 + rr)*H_ + ch*8);
    *(uint4*)(&ws[0][r*128 + sc*8]) = *(const uint4*)(Wt + (size_t)(col0 + r)*H_ + ch*8);
  }
  __syncthreads();
  int w = tid >> 6, l = tid & 63;
  int lr = l & 15, q = l >> 4;
  int arow = w*16 + lr;
  bf16x8 afr[4];
  #pragma unroll
  for (int kf = 0; kf < 4; ++kf){
    int bch = kf*4 + q;
    afr[kf] = *(const bf16x8*)(&xs[arow*128 + (bch ^ (arow & 7))*8]);
  }
  __syncthreads();                 // xs free -> C staging buffer
  unsigned short* cs = xs;         // [64][72] padded
  #pragma unroll
  for (int cbk = 0; cbk < 4; ++cbk){
    int cur = cbk & 1;
    if (cbk < 3){
      #pragma unroll
      for (int p = 0; p < 4; ++p){
        int r = r0 + p*16;
        int sc = ch ^ (r & 7);
        *(uint4*)(&ws[cur^1][r*128 + sc*8]) =
            *(const uint4*)(Wt + (size_t)(col0 + (cbk+1)*64 + r)*H_ + ch*8);
      }
    }
    f32x4 z = {0.f, 0.f, 0.f, 0.f};
    f32x4 acc[4] = {z, z, z, z};
    #pragma unroll
    for (int kf = 0; kf < 4; ++kf){
      int bch = kf*4 + q;
      #pragma unroll
      for (int cf = 0; cf < 4; ++cf){
        int brow = cf*16 + lr;
        bf16x8 bfr = *(const bf16x8*)(&ws[cur][brow*128 + (bch ^ (brow & 7))*8]);
        acc[cf] = __builtin_amdgcn_mfma_f32_16x16x32_bf16(afr[kf], bfr, acc[cf], 0, 0, 0);
      }
    }
    #pragma unroll
    for (int cf = 0; cf < 4; ++cf)
      #pragma unroll
      for (int rg = 0; rg < 4; ++rg)
        cs[(w*16 + q*4 + rg)*72 + cf*16 + lr] = f2b(acc[cf][rg]);
    __syncthreads();
    #pragma unroll
    for (int p = 0; p < 2; ++p){
      int k = tid + p*256;
      int r = k >> 3, c8 = k & 7;
      if (r < rmax){
        uint4 v = *(const uint4*)(&cs[r*72 + c8*8]);
        *(uint4*)(Hb + (row0 + r)*HH_ + col0 + cbk*64 + c8*8) = v;
      }
    }
    __syncthreads();
  }
}

// ---------------- aggregate: long phase A + pk phase B + XCD swizzle (frozen) ----------------
__global__ __launch_bounds__(256) void k_aggregate(const unsigned short* __restrict__ Hb,
    const float* __restrict__ es, const float* __restrict__ ed,
    const int* __restrict__ off, const int* __restrict__ csr,
    const float* __restrict__ bias, float* __restrict__ Y){
  int idx = blockIdx.x;
  int b = (idx & 7) >> 1;                       // graph -> XCD pair {2b, 2b+1}
  int j = ((idx >> 3) << 1) | (idx & 1);        // block within graph [0,2500)
  int lane = threadIdx.x & 63;
  int t = j*4 + (threadIdx.x >> 6);
  int gw = b*N_ + t;
  const float4 edv = *(const float4*)(ed + (size_t)gw*4);
  int start = off[b*(N_+1) + t];
  int deg = off[b*(N_+1) + t + 1] - start;
  const int* lst = csr + (size_t)b*E_ + start;

  // phase A: online softmax stats (long form — staggers waves, hides phase-B ramp)
  float m0=-1e30f, m1=-1e30f, m2=-1e30f, m3=-1e30f;
  float s0=0.f, s1=0.f, s2=0.f, s3=0.f;
  for (int i = lane; i <= deg; i += 64){
    int srcn = (i < deg) ? lst[i] : t;
    float4 ev = *(const float4*)(es + (size_t)(b*N_ + srcn)*4);
    float e0 = lrelu(ev.x + edv.x);
    float e1 = lrelu(ev.y + edv.y);
    float e2 = lrelu(ev.z + edv.z);
    float e3 = lrelu(ev.w + edv.w);
    float nm;
    nm = fmaxf(m0, e0); s0 = s0*__expf(m0-nm) + __expf(e0-nm); m0 = nm;
    nm = fmaxf(m1, e1); s1 = s1*__expf(m1-nm) + __expf(e1-nm); m1 = nm;
    nm = fmaxf(m2, e2); s2 = s2*__expf(m2-nm) + __expf(e2-nm); m2 = nm;
    nm = fmaxf(m3, e3); s3 = s3*__expf(m3-nm) + __expf(e3-nm); m3 = nm;
  }
  #pragma unroll
  for (int d = 1; d < 64; d <<= 1){
    float om, os, nm;
    om = __shfl_xor(m0, d); os = __shfl_xor(s0, d); nm = fmaxf(m0, om);
    s0 = s0*__expf(m0-nm) + os*__expf(om-nm); m0 = nm;
    om = __shfl_xor(m1, d); os = __shfl_xor(s1, d); nm = fmaxf(m1, om);
    s1 = s1*__expf(m1-nm) + os*__expf(om-nm); m1 = nm;
    om = __shfl_xor(m2, d); os = __shfl_xor(s2, d); nm = fmaxf(m2, om);
    s2 = s2*__expf(m2-nm) + os*__expf(om-nm); m2 = nm;
    om = __shfl_xor(m3, d); os = __shfl_xor(s3, d); nm = fmaxf(m3, om);
    s3 = s3*__expf(m3-nm) + os*__expf(om-nm); m3 = nm;
  }

  // phase B: weighted sum; alpha = exp(e - Lh), Lh = m + log(S)
  int head = lane >> 4;
  float mh, sh, edh;
  if      (head == 0){ mh = m0; sh = s0; edh = edv.x; }
  else if (head == 1){ mh = m1; sh = s1; edh = edv.y; }
  else if (head == 2){ mh = m2; sh = s2; edh = edv.z; }
  else               { mh = m3; sh = s3; edh = edv.w; }
  float Lh = mh + __logf(sh);
  int cb = head*H_ + (lane & 15)*8;
  const unsigned short* hbase = Hb + (size_t)b*N_*HH_;
  const float* esb = es + (size_t)b*N_*4;
  f32x2 zz = {0.f, 0.f};
  f32x2 ac[4] = {zz, zz, zz, zz};
  int total = deg + 1;    // + implicit self-loop
  int i = 0;
  for (; i + 1 < total; i += 2){
    int sA = lst[i];                       // i < deg guaranteed
    int sB = (i + 1 < deg) ? lst[i+1] : t;
    float eA = esb[(size_t)sA*4 + head];
    float eB = esb[(size_t)sB*4 + head];
    uint4 hA = *(const uint4*)(hbase + (size_t)sA*HH_ + cb);
    uint4 hB = *(const uint4*)(hbase + (size_t)sB*HH_ + cb);
    float aA = __expf(lrelu(eA + edh) - Lh);
    float aB = __expf(lrelu(eB + edh) - Lh);
    acc_row(ac, aA, hA);
    acc_row(ac, aB, hB);
  }
  if (i < total){
    int sA = (i < deg) ? lst[i] : t;
    float eA = esb[(size_t)sA*4 + head];
    uint4 hA = *(const uint4*)(hbase + (size_t)sA*HH_ + cb);
    float aA = __expf(lrelu(eA + edh) - Lh);
    acc_row(ac, aA, hA);
  }
  // head mean
  float a[8] = {ac[0].x, ac[0].y, ac[1].x, ac[1].y, ac[2].x, ac[2].y, ac[3].x, ac[3].y};
  #pragma unroll
  for (int d = 16; d < 64; d <<= 1)
    #pragma unroll
    for (int j2 = 0; j2 < 8; j2++) a[j2] += __shfl_xor(a[j2], d);
  if (lane < 16){
    int c = lane*8;
    float4 o0 = make_float4(0.25f*a[0]+bias[c+0], 0.25f*a[1]+bias[c+1],
                            0.25f*a[2]+bias[c+2], 0.25f*a[3]+bias[c+3]);
    float4 o1 = make_float4(0.25f*a[4]+bias[c+4], 0.25f*a[5]+bias[c+5],
                            0.25f*a[6]+bias[c+6], 0.25f*a[7]+bias[c+7]);
    *(float4*)(Y + (size_t)gw*H_ + c)     = o0;
    *(float4*)(Y + (size_t)gw*H_ + c + 4) = o1;
  }
}

// ---------------- fused LayerNorm+ReLU + next-layer logits (one wave per row) ----------------
__global__ __launch_bounds__(256) void k_lnrelu_logits(const float* __restrict__ Y,
    const float* __restrict__ g, const float* __restrict__ bb,
    const float* __restrict__ was, const float* __restrict__ wad,
    unsigned short* __restrict__ Xb, float* __restrict__ es, float* __restrict__ ed){
  int gw = (blockIdx.x*blockDim.x + threadIdx.x) >> 6;
  int lane = threadIdx.x & 63;
  float2 v = *(const float2*)(Y + (size_t)gw*H_ + lane*2);
  float sum = v.x + v.y;
  #pragma unroll
  for (int d = 1; d < 64; d <<= 1) sum += __shfl_xor(sum, d);
  float mu = sum * (1.f/H_);
  float dx = v.x - mu, dy = v.y - mu;
  float vs = dx*dx + dy*dy;
  #pragma unroll
  for (int d = 1; d < 64; d <<= 1) vs += __shfl_xor(vs, d);
  float inv = rsqrtf(vs*(1.f/H_) + 1e-5f);
  float2 gv = *(const float2*)(g + lane*2);
  float2 bv = *(const float2*)(bb + lane*2);
  float ox = fmaxf(dx*inv*gv.x + bv.x, 0.f);
  float oy = fmaxf(dy*inv*gv.y + bv.y, 0.f);
  unsigned int o = ((unsigned int)f2b(oy) << 16) | (unsigned int)f2b(ox);
  *(unsigned int*)(Xb + (size_t)gw*H_ + lane*2) = o;
  int c = lane*2;
  const f32x4* w4 = (const f32x4*)was;
  const f32x4* d4 = (const f32x4*)wad;
  f32x4 se = ox*w4[c] + oy*w4[c+1];
  f32x4 de = ox*d4[c] + oy*d4[c+1];
  #pragma unroll
  for (int d = 1; d < 64; d <<= 1){
    se.x += __shfl_xor(se.x,d); se.y += __shfl_xor(se.y,d);
    se.z += __shfl_xor(se.z,d); se.w += __shfl_xor(se.w,d);
    de.x += __shfl_xor(de.x,d); de.y += __shfl_xor(de.y,d);
    de.z += __shfl_xor(de.z,d); de.w += __shfl_xor(de.w,d);
  }
  if (lane == 0){
    *(float4*)(es + (size_t)gw*4) = make_float4(se.x, se.y, se.z, se.w);
    *(float4*)(ed + (size_t)gw*4) = make_float4(de.x, de.y, de.z, de.w);
  }
}

extern "C" void kernel_launch(void* const* d_in, const int* in_sizes, int n_in,
                              void* d_out, int out_size, void* d_ws, size_t ws_size,
                              hipStream_t stream){
  const float* x0   = (const float*)d_in[0];
  const int*   srcI = (const int*)d_in[1];
  const int*   tgtI = (const int*)d_in[2];
  const float* Wl[3]  = {(const float*)d_in[3], (const float*)d_in[7],  (const float*)d_in[11]};
  const float* asl[3] = {(const float*)d_in[4], (const float*)d_in[8],  (const float*)d_in[12]};
  const float* adl[3] = {(const float*)d_in[5], (const float*)d_in[9],  (const float*)d_in[13]};
  const float* bl[3]  = {(const float*)d_in[6], (const float*)d_in[10], (const float*)d_in[14]};
  const float* lng[2] = {(const float*)d_in[15], (const float*)d_in[17]};
  const float* lnb[2] = {(const float*)d_in[16], (const float*)d_in[18]};

  char* p = (char*)d_ws;
  auto carve = [&](size_t bytes) -> void* {
    void* r = (void*)p; p += (bytes + 255) & ~(size_t)255; return r;
  };
  int*   off    = (int*)carve((size_t)B_*(N_+1)*4);
  int*   cnt    = (int*)carve((size_t)B_*N_*4);
  int*   cursor = (int*)carve((size_t)B_*N_*4);
  int*   csr    = (int*)carve((size_t)B_*E_*4);
  float* es     = (float*)carve((size_t)NROWS*4*4);
  float* ed     = (float*)carve((size_t)NROWS*4*4);
  float* wasA   = (float*)carve((size_t)3*HH_*4);
  float* wadA   = (float*)carve((size_t)3*HH_*4);
  unsigned short* wtA  = (unsigned short*)carve((size_t)3*HH_*H_*2);
  unsigned short* hbuf = (unsigned short*)carve((size_t)NROWS*HH_*2);
  unsigned short* xbf  = (unsigned short*)carve((size_t)NROWS*H_*2);
  float* tbuf   = (float*)carve((size_t)NROWS*H_*4);

  hipMemsetAsync(cnt, 0, (size_t)B_*N_*4, stream);
  k_setup<<<8274, 256, 0, stream>>>(tgtI, cnt,
                                    Wl[0], Wl[1], Wl[2],
                                    asl[0], asl[1], asl[2],
                                    adl[0], adl[1], adl[2],
                                    wasA, wadA, wtA, x0, xbf);
  k_scan<<<B_, 1024, 0, stream>>>(cnt, off, cursor);
  k_misc<<<12500, 256, 0, stream>>>(srcI, tgtI, cursor, csr, xbf, wasA, wadA, es, ed);

  for (int l = 0; l < 3; ++l){
    k_gemm_mfma<<<1264, 256, 0, stream>>>(xbf, wtA + (size_t)l*HH_*H_, hbuf);
    float* yout = (l == 2) ? (float*)d_out : tbuf;
    k_aggregate<<<NROWS/4, 256, 0, stream>>>(hbuf, es, ed, off, csr, bl[l], yout);
    if (l < 2){
      k_lnrelu_logits<<<NROWS/4, 256, 0, stream>>>(tbuf, lng[l], lnb[l],
          wasA + (size_t)(l+1)*HH_, wadA + (size_t)(l+1)*HH_, xbf, es, ed);
    }
  }
}